// Round 3
// baseline (1930.143 us; speedup 1.0000x reference)
//
#include <hip/hip_runtime.h>
#include <cstdint>
#include <cstddef>

// GGNN on MI355X. Round 3: fp32-equivalent 3-limb bf16 MFMA everywhere,
// limb-products accumulated ASCENDING (corrections first) to minimize fp32
// accumulation rounding, and numpy-matching fp32 association in epilogues:
//   u3 = (h@u3w^T) + u3b   (rounded once, reused by z and r)
//   z  = sigmoid((av@w3^T + w3b) + u3)
//   r  = sigmoid((av@w4^T + w4b) + u3)
//   hv = tanh((av@w5^T + w5b) + ((r*h)@u5w^T + u5b))
//   h' = (1-z)*h + z*hv
// Layouts:
//   hN2 [b*128+d][ l0(1024) | l1(1024) | l2(1024) ]      adjacency B^T operand
//   X2  [n*32+b ][ per-limb 384: m_in(128) m_out(128) h(128) ] x3   (LDX 1152)
//   Wsm [384: w3|w4|w5][ per-limb 256 ] x3 ; u3wb/u5wb [128][ per-limb 128 ] x3
//   rh3 [n*32+b][ per-limb 128 ] x3

typedef __bf16 bf16;
typedef __attribute__((ext_vector_type(8))) __bf16 bf16x8;
typedef __attribute__((ext_vector_type(4))) __bf16 bf16x4;
typedef __attribute__((ext_vector_type(4))) float f32x4;

#define LDX 1152  // X2 row stride (3*384)
#define LDH 3072  // hN2 row stride (3*1024)

// limb-product schedule, ascending magnitude: 11, 02, 20, 01, 10, 00
static constexpr int SA[6] = {1, 0, 2, 0, 1, 0};
static constexpr int SB[6] = {1, 2, 0, 1, 0, 0};

static __device__ __forceinline__ void gload16(const void* g, void* l) {
  __builtin_amdgcn_global_load_lds(
      (const __attribute__((address_space(1))) void*)g,
      (__attribute__((address_space(3))) void*)l, 16, 0, 0);
}

static __device__ __forceinline__ float sigmoidf_(float x) {
  return 1.f / (1.f + expf(-x));
}

static __device__ __forceinline__ unsigned short bc16(bf16 x) {
  return __builtin_bit_cast(unsigned short, x);
}
static __device__ __forceinline__ bf16 bcbf(unsigned short x) {
  return __builtin_bit_cast(bf16, x);
}

// ---------------- GEMM: C = A @ W^T, 128x128 tile, 4 waves, 16x16x32 bf16 MFMA.
// 6 limb-products (ascending). A limb l at column abase + l*aLS; W limb l at l*wLS.
// STORE=0: fp32 out [M][ldc].
// STORE=2: 3-limb bf16 into X2 (adjacency epilogue): row=node n, col=b*128+d ->
//          X2[(n*32+b)*LDX + l*384 + col_off + d].
template <int STORE>
__global__ __launch_bounds__(256) void gemm_bt(const bf16* __restrict__ A, int lda,
                                               int abase, int aLS,
                                               const bf16* __restrict__ W, int ldw,
                                               int wLS,
                                               float* __restrict__ out_f,
                                               bf16* __restrict__ out_x, int ldc, int K,
                                               int col_off) {
  __shared__ bf16 lA[128 * 32];
  __shared__ bf16 lW[128 * 32];
  const int t = threadIdx.x;
  const int wave = t >> 6;
  const int lane = t & 63;
  const int wr = wave >> 1, wc = wave & 1;
  const int m0 = blockIdx.y * 128;
  const int n0 = blockIdx.x * 128;

  f32x4 acc[4][4];
#pragma unroll
  for (int i = 0; i < 4; ++i)
#pragma unroll
    for (int j = 0; j < 4; ++j) acc[i][j] = {0.f, 0.f, 0.f, 0.f};

  const int srow = (t >> 2);        // staging row within 64-row sweep
  const int scol = (t & 3) * 8;     // staging col (elems)
  const int frow = lane & 15;       // fragment row/col within 16
  const int kfr = (lane >> 4) * 8;  // fragment k offset

#pragma unroll
  for (int p = 0; p < 6; ++p) {
    const int aoff = abase + SA[p] * aLS;
    const int woff = SB[p] * wLS;
    for (int kk = 0; kk < K; kk += 32) {
      {
        const bf16* ga = A + (size_t)(m0 + srow) * lda + (aoff + kk + scol);
        bf16* la = lA + wave * 512;
        gload16(ga, la);
        gload16(ga + (size_t)64 * lda, la + 2048);
        const bf16* gw = W + (size_t)(n0 + srow) * ldw + (woff + kk + scol);
        bf16* lw = lW + wave * 512;
        gload16(gw, lw);
        gload16(gw + (size_t)64 * ldw, lw + 2048);
      }
      __syncthreads();
      bf16x8 af[4], wf[4];
#pragma unroll
      for (int m = 0; m < 4; ++m)
        af[m] = *(const bf16x8*)(lA + (wr * 64 + m * 16 + frow) * 32 + kfr);
#pragma unroll
      for (int n = 0; n < 4; ++n)
        wf[n] = *(const bf16x8*)(lW + (wc * 64 + n * 16 + frow) * 32 + kfr);
#pragma unroll
      for (int m = 0; m < 4; ++m)
#pragma unroll
        for (int n = 0; n < 4; ++n)
          acc[m][n] = __builtin_amdgcn_mfma_f32_16x16x32_bf16(af[m], wf[n], acc[m][n], 0, 0, 0);
      __syncthreads();
    }
  }

  // C/D layout (m89-verified): col = lane&15, row = (lane>>4)*4 + j
  const int rb = m0 + wr * 64 + (lane >> 4) * 4;
  const int cb = n0 + wc * 64 + (lane & 15);
#pragma unroll
  for (int m = 0; m < 4; ++m)
#pragma unroll
    for (int n = 0; n < 4; ++n)
#pragma unroll
      for (int j = 0; j < 4; ++j) {
        const int gr = rb + m * 16 + j;
        const int gc = cb + n * 16;
        const float v = acc[m][n][j];
        if (STORE == 0) {
          out_f[(size_t)gr * ldc + gc] = v;
        } else {
          const int bb = gc >> 7, d = gc & 127;
          bf16* px = out_x + ((size_t)gr * 32 + bb) * LDX + col_off + d;
          const bf16 l0 = (bf16)v;
          float r = v - (float)l0;
          const bf16 l1 = (bf16)r;
          r -= (float)l1;
          px[0] = l0;
          px[384] = l1;
          px[768] = (bf16)r;
        }
      }
}

// ---------------- pack h (fp32 [B][N][D]) -> hN2 3-limb + X2 h-columns 3-limb
__global__ __launch_bounds__(256) void pack_h(const float* __restrict__ h,
                                              bf16* __restrict__ hN2,
                                              bf16* __restrict__ X2) {
  __shared__ unsigned int lds01[128][33];
  __shared__ unsigned short lds2[128][33];
  const int t = threadIdx.x;
  const int b = blockIdx.y;
  const int n0 = blockIdx.x * 32;
#pragma unroll
  for (int i = 0; i < 16; ++i) {
    const int idx = i * 256 + t;
    const int nl = idx >> 7, d = idx & 127;
    const float v = h[((size_t)b * 1024 + n0 + nl) * 128 + d];
    const bf16 l0 = (bf16)v;
    float r = v - (float)l0;
    const bf16 l1 = (bf16)r;
    r -= (float)l1;
    const bf16 l2 = (bf16)r;
    const size_t xr = ((size_t)(n0 + nl) * 32 + b) * LDX + 256 + d;
    X2[xr] = l0;
    X2[xr + 384] = l1;
    X2[xr + 768] = l2;
    lds01[d][nl] = (unsigned)bc16(l0) | ((unsigned)bc16(l1) << 16);
    lds2[d][nl] = bc16(l2);
  }
  __syncthreads();
#pragma unroll
  for (int i = 0; i < 16; ++i) {
    const int idx = i * 256 + t;
    const int d = idx >> 5, nl = idx & 31;
    const unsigned pk = lds01[d][nl];
    const unsigned short s2 = lds2[d][nl];
    bf16* row = hN2 + (size_t)(b * 128 + d) * LDH + n0 + nl;
    row[0] = bcbf((unsigned short)(pk & 0xffffu));
    row[1024] = bcbf((unsigned short)(pk >> 16));
    row[2048] = bcbf(s2);
  }
}

// ---------------- elementwise 1: r gate -> rh3 (3-limb bf16)
__global__ __launch_bounds__(256) void ew1(const float* __restrict__ pre,
                                           const float* __restrict__ u3g,
                                           const float* __restrict__ h,
                                           const float* __restrict__ w4b,
                                           const float* __restrict__ u3b,
                                           bf16* __restrict__ rh3) {
  const int e4 = blockIdx.x * 256 + threadIdx.x;
  const int r = e4 >> 5;
  const int dq = (e4 & 31) * 4;
  const int b = r & 31, n = r >> 5;
  const f32x4 p = *(const f32x4*)(pre + (size_t)r * 384 + 128 + dq);
  const f32x4 ug = *(const f32x4*)(u3g + (size_t)r * 128 + dq);
  const f32x4 hh = *(const f32x4*)(h + ((size_t)b * 1024 + n) * 128 + dq);
  const f32x4 b4 = *(const f32x4*)(w4b + dq);
  const f32x4 b3u = *(const f32x4*)(u3b + dq);
  bf16x4 o0, o1, o2;
#pragma unroll
  for (int j = 0; j < 4; ++j) {
    const float u3f = ug[j] + b3u[j];            // np: u3 = H + u3b (rounded once)
    const float rr = sigmoidf_((p[j] + b4[j]) + u3f);
    const float v = rr * hh[j];
    o0[j] = (bf16)v;
    float res = v - (float)o0[j];
    o1[j] = (bf16)res;
    res -= (float)o1[j];
    o2[j] = (bf16)res;
  }
  *(bf16x4*)(rh3 + (size_t)r * 384 + dq) = o0;
  *(bf16x4*)(rh3 + (size_t)r * 384 + 128 + dq) = o1;
  *(bf16x4*)(rh3 + (size_t)r * 384 + 256 + dq) = o2;
}

// ---------------- elementwise 2: z, hv, h update -> out
__global__ __launch_bounds__(256) void ew2(const float* __restrict__ pre,
                                           const float* __restrict__ u3g,
                                           const float* __restrict__ u5p,
                                           const float* __restrict__ h,
                                           const float* __restrict__ w3b,
                                           const float* __restrict__ u3b,
                                           const float* __restrict__ w5b,
                                           const float* __restrict__ u5b,
                                           float* __restrict__ out) {
  const int e4 = blockIdx.x * 256 + threadIdx.x;
  const int r = e4 >> 5;
  const int dq = (e4 & 31) * 4;
  const int b = r & 31, n = r >> 5;
  const f32x4 zp = *(const f32x4*)(pre + (size_t)r * 384 + dq);
  const f32x4 hp = *(const f32x4*)(pre + (size_t)r * 384 + 256 + dq);
  const f32x4 ug = *(const f32x4*)(u3g + (size_t)r * 128 + dq);
  const f32x4 up = *(const f32x4*)(u5p + (size_t)r * 128 + dq);
  const f32x4 hh = *(const f32x4*)(h + ((size_t)b * 1024 + n) * 128 + dq);
  const f32x4 b3 = *(const f32x4*)(w3b + dq);
  const f32x4 b3u = *(const f32x4*)(u3b + dq);
  const f32x4 b5 = *(const f32x4*)(w5b + dq);
  const f32x4 b5u = *(const f32x4*)(u5b + dq);
  f32x4 o;
#pragma unroll
  for (int j = 0; j < 4; ++j) {
    const float u3f = ug[j] + b3u[j];            // same rounding as ew1
    const float z = sigmoidf_((zp[j] + b3[j]) + u3f);
    const float u5f = up[j] + b5u[j];            // np: U5 + u5b rounded
    const float hv = tanhf((hp[j] + b5[j]) + u5f);
    const float t1 = 1.f - z;
    const float t2 = t1 * hh[j];
    const float t3 = z * hv;
    o[j] = t2 + t3;                              // np: (1-z)*h + z*hv
  }
  *(f32x4*)(out + ((size_t)b * 1024 + n) * 128 + dq) = o;
}

// ---------------- init kernels
__global__ __launch_bounds__(256) void split_adj(const float* __restrict__ src,
                                                 bf16* __restrict__ dst) {
  const int i = blockIdx.x * 256 + threadIdx.x;  // 1M
  const int r = i >> 10, c = i & 1023;
  const float v = src[i];
  const bf16 l0 = (bf16)v;
  float rr = v - (float)l0;
  const bf16 l1 = (bf16)rr;
  rr -= (float)l1;
  dst[(size_t)r * 3072 + c] = l0;
  dst[(size_t)r * 3072 + 1024 + c] = l1;
  dst[(size_t)r * 3072 + 2048 + c] = (bf16)rr;
}

// Wsm [384 rows: w3|w4|w5][ limb*256 + k ]
__global__ void build_wsm(const float* __restrict__ w3, const float* __restrict__ w4,
                          const float* __restrict__ w5, bf16* __restrict__ Wsm) {
  const int k = blockIdx.x * 128 + threadIdx.x;  // 0..255
  const int j = blockIdx.y;                      // 0..383
  float v;
  if (j < 128) v = w3[j * 256 + k];
  else if (j < 256) v = w4[(j - 128) * 256 + k];
  else v = w5[(j - 256) * 256 + k];
  const bf16 l0 = (bf16)v;
  float rr = v - (float)l0;
  const bf16 l1 = (bf16)rr;
  rr -= (float)l1;
  bf16* row = Wsm + (size_t)j * 768 + k;
  row[0] = l0;
  row[256] = l1;
  row[512] = (bf16)rr;
}

// u-weight [128][ limb*128 + k ]
__global__ void build_uw(const float* __restrict__ u, bf16* __restrict__ dst) {
  const int i = blockIdx.x * 256 + threadIdx.x;  // 16384
  const int j = i >> 7, k = i & 127;
  const float v = u[i];
  const bf16 l0 = (bf16)v;
  float rr = v - (float)l0;
  const bf16 l1 = (bf16)rr;
  rr -= (float)l1;
  bf16* row = dst + (size_t)j * 384 + k;
  row[0] = l0;
  row[128] = l1;
  row[256] = (bf16)rr;
}

__global__ void sentinel(float* out, int n) {
  const int i = blockIdx.x * 256 + threadIdx.x;
  if (i < n) out[i] = 123456789.f;
}

extern "C" void kernel_launch(void* const* d_in, const int* in_sizes, int n_in,
                              void* d_out, int out_size, void* d_ws, size_t ws_size,
                              hipStream_t stream) {
  const float* input = (const float*)d_in[0];
  const float* Ain = (const float*)d_in[1];
  const float* Aout = (const float*)d_in[2];
  const float* w3w = (const float*)d_in[3];
  const float* w3b = (const float*)d_in[4];
  const float* u3w = (const float*)d_in[5];
  const float* u3b = (const float*)d_in[6];
  const float* w4w = (const float*)d_in[7];
  const float* w4b = (const float*)d_in[8];  // unused by ref formula? kept: np adds w4b
  const float* w5w = (const float*)d_in[9];
  const float* w5b = (const float*)d_in[10];
  const float* u5wf = (const float*)d_in[11];
  const float* u5b = (const float*)d_in[12];
  // d_in[13] = time_step; fixed at 5 by the problem spec.

  char* ws = (char*)d_ws;
  size_t off = 0;
  auto alloc = [&](size_t bytes) -> void* {
    void* p = ws + off;
    off += (bytes + 255) & ~(size_t)255;
    return p;
  };
  bf16* A2in = (bf16*)alloc(1024ull * 3072 * 2);
  bf16* A2out = (bf16*)alloc(1024ull * 3072 * 2);
  bf16* hN2 = (bf16*)alloc(4096ull * 3072 * 2);
  bf16* X2 = (bf16*)alloc(32768ull * 1152 * 2);
  bf16* Wsm = (bf16*)alloc(384ull * 768 * 2);
  bf16* u3wb = (bf16*)alloc(128ull * 384 * 2);
  bf16* u5wb = (bf16*)alloc(128ull * 384 * 2);
  float* pre = (float*)alloc(32768ull * 384 * 4);
  float* u3g = (float*)alloc(32768ull * 128 * 4);
  // Overlays (stream-sequential lifetimes verified):
  //  rh3 (25.17MB) = hN2 (25.17MB): ew1 writes after adj GEMMs read hN2;
  //      pack_h fully rewrites hN2 next step before adj reads.
  //  u5p (16.8MB) = X2 head (75.5MB): u5-GEMM writes after W/U3 GEMMs read X2;
  //      pack_h + adj epilogues fully rewrite X2 next step before W/U3 read.
  bf16* rh3 = hN2;
  float* u5p = (float*)X2;
  if (off > ws_size) {  // distinct "workspace too small" signal
    sentinel<<<dim3((out_size + 255) / 256), dim3(256), 0, stream>>>((float*)d_out, out_size);
    return;
  }

  split_adj<<<dim3(4096), dim3(256), 0, stream>>>(Ain, A2in);
  split_adj<<<dim3(4096), dim3(256), 0, stream>>>(Aout, A2out);
  build_wsm<<<dim3(2, 384), dim3(128), 0, stream>>>(w3w, w4w, w5w, Wsm);
  build_uw<<<dim3(64), dim3(256), 0, stream>>>(u3w, u3wb);
  build_uw<<<dim3(64), dim3(256), 0, stream>>>(u5wf, u5wb);

  float* out = (float*)d_out;
  const float* h = input;
  for (int step = 0; step < 5; ++step) {
    pack_h<<<dim3(32, 32), dim3(256), 0, stream>>>(h, hN2, X2);
    // m_in -> X2 limb-cols [0:128], m_out -> [128:256]
    gemm_bt<2><<<dim3(32, 8), dim3(256), 0, stream>>>(A2in, 3072, 0, 1024, hN2, 3072, 1024,
                                                      nullptr, X2, 0, 1024, 0);
    gemm_bt<2><<<dim3(32, 8), dim3(256), 0, stream>>>(A2out, 3072, 0, 1024, hN2, 3072, 1024,
                                                      nullptr, X2, 0, 1024, 128);
    // pre[32768][384] = av @ [w3;w4;w5]^T  (K=256, av = X2 limb-cols [0:256))
    gemm_bt<0><<<dim3(3, 256), dim3(256), 0, stream>>>(X2, LDX, 0, 384, Wsm, 768, 256,
                                                       pre, nullptr, 384, 256, 0);
    // u3g[32768][128] = h @ u3w^T  (K=128, h = X2 limb-cols [256:384))
    gemm_bt<0><<<dim3(1, 256), dim3(256), 0, stream>>>(X2, LDX, 256, 384, u3wb, 384, 128,
                                                       u3g, nullptr, 128, 128, 0);
    ew1<<<dim3(4096), dim3(256), 0, stream>>>(pre, u3g, h, w4b, u3b, rh3);
    // u5p = (r*h) @ u5w^T  (K=128)
    gemm_bt<0><<<dim3(1, 256), dim3(256), 0, stream>>>(rh3, 384, 0, 128, u5wb, 384, 128,
                                                       u5p, nullptr, 128, 128, 0);
    ew2<<<dim3(4096), dim3(256), 0, stream>>>(pre, u3g, u5p, h, w3b, u3b, w5b, u5b, out);
    h = out;
  }
}

// Round 4
// 1474.883 us; speedup vs baseline: 1.3087x; 1.3087x over previous
//
#include <hip/hip_runtime.h>
#include <cstdint>
#include <cstddef>

// GGNN on MI355X. Round 4: same fp32-equivalent 3-limb numerics as round 3
// (absmax 0.0156), restructured for occupancy:
//  - adjacency: A_in/A_out merged (M=2048) + split-K by limb-product tier:
//      dispatch1 (32,16,2): chunk0={11,02,20}, chunk1={01,10} -> fp32 partials
//      dispatch2 (32,16):   {00}, epilogue v=(p0+p1)+acc00 (ascending) + X2 split
//  - dense: W-part (K=256) and u3-part (K=128) merged in one (4,256) dispatch
//  - u5 GEMM epilogue fuses ew2 (z, hv, h' update) -> writes d_out directly
// Layouts (unchanged):
//   A2  [2048: Ain|Aout][ l0(1024)|l1(1024)|l2(1024) ]
//   hN2 [b*128+d][ l0|l1|l2 (1024 each) ]   (adjacency B^T operand; rh3 overlay)
//   X2  [n*32+b][ per-limb 384: m_in(128) m_out(128) h(128) ] x3  (LDX 1152)
//   Wsm [384: w3|w4|w5][ per-limb 256 ] ; u3wb/u5wb [128][ per-limb 128 ]
//   pre/u3f fp32; pbuf (2 partial chunks) overlays pre+u3f exactly (67.1MB)

typedef __bf16 bf16;
typedef __attribute__((ext_vector_type(8))) __bf16 bf16x8;
typedef __attribute__((ext_vector_type(4))) __bf16 bf16x4;
typedef __attribute__((ext_vector_type(4))) float f32x4;

#define LDX 1152
#define LDH 3072
#define PCHUNK (2048ull * 4096ull)

// limb-product schedule for 6-product GEMMs, ascending: 11,02,20,01,10,00
static constexpr int SA6[6] = {1, 0, 2, 0, 1, 0};
static constexpr int SB6[6] = {1, 2, 0, 1, 0, 0};

static __device__ __forceinline__ void gload16(const void* g, void* l) {
  __builtin_amdgcn_global_load_lds(
      (const __attribute__((address_space(1))) void*)g,
      (__attribute__((address_space(3))) void*)l, 16, 0, 0);
}

static __device__ __forceinline__ float sigmoidf_(float x) {
  return 1.f / (1.f + expf(-x));
}

static __device__ __forceinline__ unsigned short bc16(bf16 x) {
  return __builtin_bit_cast(unsigned short, x);
}
static __device__ __forceinline__ bf16 bcbf(unsigned short x) {
  return __builtin_bit_cast(bf16, x);
}

// ---- GEMM inner segment: 128x128 tile, 4 waves, Kseg/32 iters of 16x16x32 bf16
// Ao/Wo already offset to (tile row 0, k 0) of this segment.
static __device__ __forceinline__ void gemm_seg(const bf16* __restrict__ Ao, int lda,
                                                const bf16* __restrict__ Wo, int ldw,
                                                int Kseg, bf16* lA, bf16* lW,
                                                f32x4 (&acc)[4][4]) {
  const int t = threadIdx.x;
  const int wave = t >> 6, lane = t & 63;
  const int wr = wave >> 1, wc = wave & 1;
  const int srow = t >> 2, scol = (t & 3) * 8;
  const int frow = lane & 15, kfr = (lane >> 4) * 8;
  for (int kk = 0; kk < Kseg; kk += 32) {
    const bf16* ga = Ao + (size_t)srow * lda + kk + scol;
    bf16* la = lA + wave * 512;
    gload16(ga, la);
    gload16(ga + (size_t)64 * lda, la + 2048);
    const bf16* gw = Wo + (size_t)srow * ldw + kk + scol;
    bf16* lw = lW + wave * 512;
    gload16(gw, lw);
    gload16(gw + (size_t)64 * ldw, lw + 2048);
    __syncthreads();
    bf16x8 af[4], wf[4];
#pragma unroll
    for (int m = 0; m < 4; ++m)
      af[m] = *(const bf16x8*)(lA + (wr * 64 + m * 16 + frow) * 32 + kfr);
#pragma unroll
    for (int n = 0; n < 4; ++n)
      wf[n] = *(const bf16x8*)(lW + (wc * 64 + n * 16 + frow) * 32 + kfr);
#pragma unroll
    for (int m = 0; m < 4; ++m)
#pragma unroll
      for (int n = 0; n < 4; ++n)
        acc[m][n] = __builtin_amdgcn_mfma_f32_16x16x32_bf16(af[m], wf[n], acc[m][n], 0, 0, 0);
    __syncthreads();
  }
}

#define ACC_ZERO(acc)                          \
  _Pragma("unroll") for (int i = 0; i < 4; ++i) \
  _Pragma("unroll") for (int j = 0; j < 4; ++j) acc[i][j] = {0.f, 0.f, 0.f, 0.f};

// C/D layout (m89-verified): col = lane&15, row = (lane>>4)*4 + j
#define EPILOG_IDX                                          \
  const int t = threadIdx.x;                                \
  const int wave = t >> 6, lane = t & 63;                   \
  const int rb = (wave >> 1) * 64 + (lane >> 4) * 4;        \
  const int cb = (wave & 1) * 64 + (lane & 15);

// ---------------- adjacency partial chunks (correction limb-products)
__global__ __launch_bounds__(256) void adj_partial(const bf16* __restrict__ A2,
                                                   const bf16* __restrict__ hN2,
                                                   float* __restrict__ pbuf) {
  __shared__ bf16 lA[4096];
  __shared__ bf16 lW[4096];
  const int m0 = blockIdx.y * 128, n0 = blockIdx.x * 128;
  f32x4 acc[4][4];
  ACC_ZERO(acc);
  const bf16* Ab = A2 + (size_t)m0 * LDH;
  const bf16* Wb = hN2 + (size_t)n0 * LDH;
  if (blockIdx.z == 0) {  // 1x1, 0x2, 2x0  (~2^-16 tier)
    gemm_seg(Ab + 1024, LDH, Wb + 1024, LDH, 1024, lA, lW, acc);
    gemm_seg(Ab, LDH, Wb + 2048, LDH, 1024, lA, lW, acc);
    gemm_seg(Ab + 2048, LDH, Wb, LDH, 1024, lA, lW, acc);
  } else {  // 0x1, 1x0  (~2^-8 tier)
    gemm_seg(Ab, LDH, Wb + 1024, LDH, 1024, lA, lW, acc);
    gemm_seg(Ab + 1024, LDH, Wb, LDH, 1024, lA, lW, acc);
  }
  float* p = pbuf + (size_t)blockIdx.z * PCHUNK;
  EPILOG_IDX;
#pragma unroll
  for (int m = 0; m < 4; ++m)
#pragma unroll
    for (int n = 0; n < 4; ++n)
#pragma unroll
      for (int j = 0; j < 4; ++j)
        p[(size_t)(m0 + rb + m * 16 + j) * 4096 + n0 + cb + n * 16] = acc[m][n][j];
}

// ---------------- adjacency main product + reduce + 3-limb X2 split
__global__ __launch_bounds__(256) void adj_final(const bf16* __restrict__ A2,
                                                 const bf16* __restrict__ hN2,
                                                 const float* __restrict__ pbuf,
                                                 bf16* __restrict__ X2) {
  __shared__ bf16 lA[4096];
  __shared__ bf16 lW[4096];
  const int m0 = blockIdx.y * 128, n0 = blockIdx.x * 128;
  f32x4 acc[4][4];
  ACC_ZERO(acc);
  gemm_seg(A2 + (size_t)m0 * LDH, LDH, hN2 + (size_t)n0 * LDH, LDH, 1024, lA, lW, acc);
  EPILOG_IDX;
#pragma unroll
  for (int m = 0; m < 4; ++m)
#pragma unroll
    for (int n = 0; n < 4; ++n)
#pragma unroll
      for (int j = 0; j < 4; ++j) {
        const int gr = m0 + rb + m * 16 + j;
        const int gc = n0 + cb + n * 16;
        const size_t idx = (size_t)gr * 4096 + gc;
        // ascending: (tiny-tier + mid-tier) + main product
        const float v = (pbuf[idx] + pbuf[idx + PCHUNK]) + acc[m][n][j];
        const int node = gr & 1023;
        const int coff = (gr >> 10) * 128;  // 0: m_in, 128: m_out
        const int bb = gc >> 7, d = gc & 127;
        bf16* px = X2 + ((size_t)node * 32 + bb) * LDX + coff + d;
        const bf16 l0 = (bf16)v;
        float r = v - (float)l0;
        const bf16 l1 = (bf16)r;
        r -= (float)l1;
        px[0] = l0;
        px[384] = l1;
        px[768] = (bf16)r;
      }
}

// ---------------- dense: bx<3 -> pre[.][bx*128..] = av@{w3,w4,w5}^T ; bx==3 -> u3f
__global__ __launch_bounds__(256) void dense_gemm(const bf16* __restrict__ X2,
                                                  const bf16* __restrict__ Wsm,
                                                  const bf16* __restrict__ u3wb,
                                                  const float* __restrict__ u3b,
                                                  float* __restrict__ pre,
                                                  float* __restrict__ u3f) {
  __shared__ bf16 lA[4096];
  __shared__ bf16 lW[4096];
  const int m0 = blockIdx.y * 128;
  const int bx = blockIdx.x;
  f32x4 acc[4][4];
  ACC_ZERO(acc);
  if (bx < 3) {
    const bf16* Ab = X2 + (size_t)m0 * LDX;
    const bf16* Wb = Wsm + (size_t)(bx * 128) * 768;
#pragma unroll
    for (int p = 0; p < 6; ++p)
      gemm_seg(Ab + SA6[p] * 384, LDX, Wb + SB6[p] * 256, 768, 256, lA, lW, acc);
    EPILOG_IDX;
#pragma unroll
    for (int m = 0; m < 4; ++m)
#pragma unroll
      for (int n = 0; n < 4; ++n)
#pragma unroll
        for (int j = 0; j < 4; ++j)
          pre[(size_t)(m0 + rb + m * 16 + j) * 384 + bx * 128 + cb + n * 16] = acc[m][n][j];
  } else {
    const bf16* Ab = X2 + (size_t)m0 * LDX + 256;
#pragma unroll
    for (int p = 0; p < 6; ++p)
      gemm_seg(Ab + SA6[p] * 384, LDX, u3wb + SB6[p] * 128, 384, 128, lA, lW, acc);
    EPILOG_IDX;
#pragma unroll
    for (int m = 0; m < 4; ++m)
#pragma unroll
      for (int n = 0; n < 4; ++n)
#pragma unroll
        for (int j = 0; j < 4; ++j) {
          const int gc = cb + n * 16;
          // np: u3 = (h@u3w^T) + u3b, rounded once
          u3f[(size_t)(m0 + rb + m * 16 + j) * 128 + gc] = acc[m][n][j] + u3b[gc];
        }
  }
}

// ---------------- u5 GEMM + fused ew2 epilogue (z, hv, h' -> out)
__global__ __launch_bounds__(256) void u5_gemm(const bf16* __restrict__ rh3,
                                               const bf16* __restrict__ u5wb,
                                               const float* __restrict__ pre,
                                               const float* __restrict__ u3f,
                                               const float* __restrict__ h,
                                               const float* __restrict__ w3b,
                                               const float* __restrict__ w5b,
                                               const float* __restrict__ u5b,
                                               float* __restrict__ out) {
  __shared__ bf16 lA[4096];
  __shared__ bf16 lW[4096];
  const int m0 = blockIdx.y * 128;
  f32x4 acc[4][4];
  ACC_ZERO(acc);
  const bf16* Ab = rh3 + (size_t)m0 * 384;
#pragma unroll
  for (int p = 0; p < 6; ++p)
    gemm_seg(Ab + SA6[p] * 128, 384, u5wb + SB6[p] * 128, 384, 128, lA, lW, acc);
  EPILOG_IDX;
#pragma unroll
  for (int m = 0; m < 4; ++m)
#pragma unroll
    for (int n = 0; n < 4; ++n)
#pragma unroll
      for (int j = 0; j < 4; ++j) {
        const int gr = m0 + rb + m * 16 + j;
        const int gc = cb + n * 16;
        const float u5f = acc[m][n][j] + u5b[gc];  // np: U5 + u5b
        const float z = sigmoidf_((pre[(size_t)gr * 384 + gc] + w3b[gc]) +
                                  u3f[(size_t)gr * 128 + gc]);
        const float hv = tanhf((pre[(size_t)gr * 384 + 256 + gc] + w5b[gc]) + u5f);
        const int bb = gr & 31, node = gr >> 5;
        const size_t hi = ((size_t)bb * 1024 + node) * 128 + gc;
        const float hh = h[hi];
        out[hi] = (1.f - z) * hh + z * hv;  // np: (1-z)*h + z*hv
      }
}

// ---------------- pack h (fp32 [B][N][D]) -> hN2 3-limb + X2 h-columns 3-limb
__global__ __launch_bounds__(256) void pack_h(const float* __restrict__ h,
                                              bf16* __restrict__ hN2,
                                              bf16* __restrict__ X2) {
  __shared__ unsigned int lds01[128][33];
  __shared__ unsigned short lds2[128][33];
  const int t = threadIdx.x;
  const int b = blockIdx.y;
  const int n0 = blockIdx.x * 32;
#pragma unroll
  for (int i = 0; i < 16; ++i) {
    const int idx = i * 256 + t;
    const int nl = idx >> 7, d = idx & 127;
    const float v = h[((size_t)b * 1024 + n0 + nl) * 128 + d];
    const bf16 l0 = (bf16)v;
    float r = v - (float)l0;
    const bf16 l1 = (bf16)r;
    r -= (float)l1;
    const bf16 l2 = (bf16)r;
    const size_t xr = ((size_t)(n0 + nl) * 32 + b) * LDX + 256 + d;
    X2[xr] = l0;
    X2[xr + 384] = l1;
    X2[xr + 768] = l2;
    lds01[d][nl] = (unsigned)bc16(l0) | ((unsigned)bc16(l1) << 16);
    lds2[d][nl] = bc16(l2);
  }
  __syncthreads();
#pragma unroll
  for (int i = 0; i < 16; ++i) {
    const int idx = i * 256 + t;
    const int d = idx >> 5, nl = idx & 31;
    const unsigned pk = lds01[d][nl];
    const unsigned short s2 = lds2[d][nl];
    bf16* row = hN2 + (size_t)(b * 128 + d) * LDH + n0 + nl;
    row[0] = bcbf((unsigned short)(pk & 0xffffu));
    row[1024] = bcbf((unsigned short)(pk >> 16));
    row[2048] = bcbf(s2);
  }
}

// ---------------- elementwise: r gate -> rh3 (3-limb bf16)
__global__ __launch_bounds__(256) void ew1(const float* __restrict__ pre,
                                           const float* __restrict__ u3f,
                                           const float* __restrict__ h,
                                           const float* __restrict__ w4b,
                                           bf16* __restrict__ rh3) {
  const int e4 = blockIdx.x * 256 + threadIdx.x;
  const int r = e4 >> 5;
  const int dq = (e4 & 31) * 4;
  const int b = r & 31, n = r >> 5;
  const f32x4 p = *(const f32x4*)(pre + (size_t)r * 384 + 128 + dq);
  const f32x4 uf = *(const f32x4*)(u3f + (size_t)r * 128 + dq);
  const f32x4 hh = *(const f32x4*)(h + ((size_t)b * 1024 + n) * 128 + dq);
  const f32x4 b4 = *(const f32x4*)(w4b + dq);
  bf16x4 o0, o1, o2;
#pragma unroll
  for (int j = 0; j < 4; ++j) {
    const float rr = sigmoidf_((p[j] + b4[j]) + uf[j]);
    const float v = rr * hh[j];
    o0[j] = (bf16)v;
    float res = v - (float)o0[j];
    o1[j] = (bf16)res;
    res -= (float)o1[j];
    o2[j] = (bf16)res;
  }
  *(bf16x4*)(rh3 + (size_t)r * 384 + dq) = o0;
  *(bf16x4*)(rh3 + (size_t)r * 384 + 128 + dq) = o1;
  *(bf16x4*)(rh3 + (size_t)r * 384 + 256 + dq) = o2;
}

// ---------------- init kernels
__global__ __launch_bounds__(256) void split_adj(const float* __restrict__ src,
                                                 bf16* __restrict__ dst) {
  const int i = blockIdx.x * 256 + threadIdx.x;  // 1M
  const int r = i >> 10, c = i & 1023;
  const float v = src[i];
  const bf16 l0 = (bf16)v;
  float rr = v - (float)l0;
  const bf16 l1 = (bf16)rr;
  rr -= (float)l1;
  dst[(size_t)r * LDH + c] = l0;
  dst[(size_t)r * LDH + 1024 + c] = l1;
  dst[(size_t)r * LDH + 2048 + c] = (bf16)rr;
}

__global__ void build_wsm(const float* __restrict__ w3, const float* __restrict__ w4,
                          const float* __restrict__ w5, bf16* __restrict__ Wsm) {
  const int k = blockIdx.x * 128 + threadIdx.x;  // 0..255
  const int j = blockIdx.y;                      // 0..383
  float v;
  if (j < 128) v = w3[j * 256 + k];
  else if (j < 256) v = w4[(j - 128) * 256 + k];
  else v = w5[(j - 256) * 256 + k];
  const bf16 l0 = (bf16)v;
  float rr = v - (float)l0;
  const bf16 l1 = (bf16)rr;
  rr -= (float)l1;
  bf16* row = Wsm + (size_t)j * 768 + k;
  row[0] = l0;
  row[256] = l1;
  row[512] = (bf16)rr;
}

__global__ void build_uw(const float* __restrict__ u, bf16* __restrict__ dst) {
  const int i = blockIdx.x * 256 + threadIdx.x;  // 16384
  const int j = i >> 7, k = i & 127;
  const float v = u[i];
  const bf16 l0 = (bf16)v;
  float rr = v - (float)l0;
  const bf16 l1 = (bf16)rr;
  rr -= (float)l1;
  bf16* row = dst + (size_t)j * 384 + k;
  row[0] = l0;
  row[128] = l1;
  row[256] = (bf16)rr;
}

__global__ void sentinel(float* out, int n) {
  const int i = blockIdx.x * 256 + threadIdx.x;
  if (i < n) out[i] = 123456789.f;
}

extern "C" void kernel_launch(void* const* d_in, const int* in_sizes, int n_in,
                              void* d_out, int out_size, void* d_ws, size_t ws_size,
                              hipStream_t stream) {
  const float* input = (const float*)d_in[0];
  const float* Ain = (const float*)d_in[1];
  const float* Aout = (const float*)d_in[2];
  const float* w3w = (const float*)d_in[3];
  const float* w3b = (const float*)d_in[4];
  const float* u3w = (const float*)d_in[5];
  const float* u3b = (const float*)d_in[6];
  const float* w4w = (const float*)d_in[7];
  const float* w4b = (const float*)d_in[8];
  const float* w5w = (const float*)d_in[9];
  const float* w5b = (const float*)d_in[10];
  const float* u5wf = (const float*)d_in[11];
  const float* u5b = (const float*)d_in[12];
  // d_in[13] = time_step; fixed at 5 by the problem spec.

  char* ws = (char*)d_ws;
  size_t off = 0;
  auto alloc = [&](size_t bytes) -> void* {
    void* p = ws + off;
    off += (bytes + 255) & ~(size_t)255;
    return p;
  };
  bf16* A2 = (bf16*)alloc(2048ull * LDH * 2);     // 12.58 MB
  bf16* hN2 = (bf16*)alloc(4096ull * LDH * 2);    // 25.17 MB (rh3 overlay)
  bf16* X2 = (bf16*)alloc(32768ull * LDX * 2);    // 75.50 MB
  bf16* Wsm = (bf16*)alloc(384ull * 768 * 2);
  bf16* u3wb = (bf16*)alloc(128ull * 384 * 2);
  bf16* u5wb = (bf16*)alloc(128ull * 384 * 2);
  float* prebuf = (float*)alloc(2 * PCHUNK * 4);  // 67.11 MB = pre(50.33)+u3f(16.78)
  float* pre = prebuf;
  float* u3f = prebuf + 32768ull * 384;
  float* pbuf = prebuf;  // partials overlay pre+u3f (lifetime-disjoint, stream-ordered)
  bf16* rh3 = hN2;       // 25.17 MB, exact-size overlay, lifetime-disjoint
  if (off > ws_size) {   // distinct "workspace too small" signal
    sentinel<<<dim3((out_size + 255) / 256), dim3(256), 0, stream>>>((float*)d_out, out_size);
    return;
  }

  split_adj<<<dim3(4096), dim3(256), 0, stream>>>(Ain, A2);
  split_adj<<<dim3(4096), dim3(256), 0, stream>>>(Aout, A2 + 1024ull * LDH);
  build_wsm<<<dim3(2, 384), dim3(128), 0, stream>>>(w3w, w4w, w5w, Wsm);
  build_uw<<<dim3(64), dim3(256), 0, stream>>>(u3w, u3wb);
  build_uw<<<dim3(64), dim3(256), 0, stream>>>(u5wf, u5wb);

  float* out = (float*)d_out;
  const float* h = input;
  for (int step = 0; step < 5; ++step) {
    pack_h<<<dim3(32, 32), dim3(256), 0, stream>>>(h, hN2, X2);
    adj_partial<<<dim3(32, 16, 2), dim3(256), 0, stream>>>(A2, hN2, pbuf);
    adj_final<<<dim3(32, 16), dim3(256), 0, stream>>>(A2, hN2, pbuf, X2);
    dense_gemm<<<dim3(4, 256), dim3(256), 0, stream>>>(X2, Wsm, u3wb, u3b, pre, u3f);
    ew1<<<dim3(4096), dim3(256), 0, stream>>>(pre, u3f, h, w4b, rh3);
    u5_gemm<<<dim3(1, 256), dim3(256), 0, stream>>>(rh3, u5wb, pre, u3f, h, w3b, w5b,
                                                    u5b, out);
    h = out;
  }
}

// Round 5
// 1442.667 us; speedup vs baseline: 1.3379x; 1.0223x over previous
//
#include <hip/hip_runtime.h>
#include <cstdint>
#include <cstddef>

// GGNN on MI355X. Round 5: numerics identical to rounds 3/4 (3-limb bf16,
// 6 limb-products ascending {11,02,20,01,10,00}, fp32-equivalent).
// Adjacency GEMM rebuilt as an 8-phase-style counted-vmcnt schedule (T2+T3+T4+T5):
//   tile 256x128, 8 waves (2Mx4N), BK=64, LDS dbuf 96KB, raw s_barrier,
//   vmcnt(6) steady (1 K-tile = 6 per-wave gload_lds in flight),
//   XOR swizzle slot^=(row&7): linear LDS dest + inverse-swizzled global src
//   + swizzled ds_read (bank-conflict-free, 2-way max).
// Epilogue does the 3-limb X2 split directly (adj_final + pbuf deleted).
// Layouts:
//   A2  [2048: Ain|Aout][ l0|l1|l2 (1024 each) ]
//   hN2 [b*128+d][ l0|l1|l2 ]  (adjacency B^T operand; rh3 overlay)
//   X2  [n*32+b][ per-limb 384: m_in(128) m_out(128) h(128) ] x3  (LDX 1152)

typedef __bf16 bf16;
typedef __attribute__((ext_vector_type(8))) __bf16 bf16x8;
typedef __attribute__((ext_vector_type(4))) __bf16 bf16x4;
typedef __attribute__((ext_vector_type(4))) float f32x4;

#define LDX 1152
#define LDH 3072
#define NT 96  // 6 products x (K=1024)/(BK=64)

// ascending limb-product schedule: 11,02,20,01,10,00
static constexpr int SA6[6] = {1, 0, 2, 0, 1, 0};
static constexpr int SB6[6] = {1, 2, 0, 1, 0, 0};

static __device__ __forceinline__ void gload16(const void* g, void* l) {
  __builtin_amdgcn_global_load_lds(
      (const __attribute__((address_space(1))) void*)g,
      (__attribute__((address_space(3))) void*)l, 16, 0, 0);
}

static __device__ __forceinline__ float sigmoidf_(float x) {
  return 1.f / (1.f + expf(-x));
}

static __device__ __forceinline__ unsigned short bc16(bf16 x) {
  return __builtin_bit_cast(unsigned short, x);
}
static __device__ __forceinline__ bf16 bcbf(unsigned short x) {
  return __builtin_bit_cast(bf16, x);
}

// ================= adjacency: 256x128 tile, 8 waves, counted-vmcnt schedule
__global__ __launch_bounds__(512) void adj8(const bf16* __restrict__ A2,
                                            const bf16* __restrict__ hN2,
                                            bf16* __restrict__ X2) {
  __shared__ bf16 sA[2][256 * 64];
  __shared__ bf16 sB[2][128 * 64];
  const int t = threadIdx.x;
  const int wave = t >> 6, lane = t & 63;
  const int wr = wave >> 2;  // 0..1  (M half: 128 rows)
  const int wn = wave & 3;   // 0..3  (N quarter: 32 cols)
  const int m0 = blockIdx.y * 256;
  const int n0 = blockIdx.x * 128;

  f32x4 acc[8][2];
#pragma unroll
  for (int i = 0; i < 8; ++i)
#pragma unroll
    for (int j = 0; j < 2; ++j) acc[i][j] = {0.f, 0.f, 0.f, 0.f};

  // ---- staging: per K-tile = 4 A-gloads + 2 B-gloads per wave (6 vmcnt units)
  // lane t covers (row = g*64 + t>>3, physical 16B slot = t&7); the slot's DATA
  // is the inverse-swizzled global slot (t&7)^(row&7). LDS dest stays linear.
  const int srow = t >> 3;                 // 0..63 within a 64-row chunk
  const int sslot = (t & 7) ^ (srow & 7);  // pre-swizzled global 16B slot
  const int wbase = wave * 512;            // elems; wave-uniform LDS base

#define STAGE(buf, kt)                                                              \
  {                                                                                 \
    const int p_ = (kt) >> 4;                                                       \
    const int k0_ = ((kt) & 15) << 6;                                               \
    const int aoff_ = SA6[p_] * 1024 + k0_ + sslot * 8;                             \
    const int boff_ = SB6[p_] * 1024 + k0_ + sslot * 8;                             \
    _Pragma("unroll") for (int g = 0; g < 4; ++g)                                   \
        gload16(A2 + (size_t)(m0 + g * 64 + srow) * LDH + aoff_,                    \
                &sA[buf][g * 4096 + wbase]);                                        \
    _Pragma("unroll") for (int g = 0; g < 2; ++g)                                   \
        gload16(hN2 + (size_t)(n0 + g * 64 + srow) * LDH + boff_,                   \
                &sB[buf][g * 4096 + wbase]);                                        \
  }

  const int frow = lane & 15;
  const int fk = lane >> 4;  // 0..3 (16B slot within K=64 row before swizzle)

  STAGE(0, 0);
  STAGE(1, 1);

  for (int kt = 0; kt < NT; ++kt) {
    const int cur = kt & 1;
    if (kt < NT - 1)
      asm volatile("s_waitcnt vmcnt(6)" ::: "memory");
    else
      asm volatile("s_waitcnt vmcnt(0)" ::: "memory");
    __builtin_amdgcn_s_barrier();
    asm volatile("" ::: "memory");  // keep ds_reads below the barrier

    // B fragments for the whole K-tile (2 nfrag x 2 kslots)
    bf16x8 bF[2][2];
#pragma unroll
    for (int nf = 0; nf < 2; ++nf)
#pragma unroll
      for (int ks = 0; ks < 2; ++ks) {
        const int row = wn * 32 + nf * 16 + frow;
        const int slot = ((ks << 2) + fk) ^ (row & 7);
        bF[nf][ks] = *(const bf16x8*)&sB[cur][row * 64 + slot * 8];
      }

#pragma unroll
    for (int q = 0; q < 4; ++q) {
      bf16x8 aF[2][2];
#pragma unroll
      for (int mi = 0; mi < 2; ++mi)
#pragma unroll
        for (int ks = 0; ks < 2; ++ks) {
          const int row = wr * 128 + (2 * q + mi) * 16 + frow;
          const int slot = ((ks << 2) + fk) ^ (row & 7);
          aF[mi][ks] = *(const bf16x8*)&sA[cur][row * 64 + slot * 8];
        }
      __builtin_amdgcn_s_barrier();
      __builtin_amdgcn_s_setprio(1);
#pragma unroll
      for (int mi = 0; mi < 2; ++mi)
#pragma unroll
        for (int nf = 0; nf < 2; ++nf)
#pragma unroll
          for (int ks = 0; ks < 2; ++ks)
            acc[2 * q + mi][nf] = __builtin_amdgcn_mfma_f32_16x16x32_bf16(
                aF[mi][ks], bF[nf][ks], acc[2 * q + mi][nf], 0, 0, 0);
      __builtin_amdgcn_s_setprio(0);
      __builtin_amdgcn_s_barrier();
      asm volatile("" ::: "memory");
    }
    if (kt + 2 < NT) STAGE(cur, kt + 2);  // buf[cur] free: all reads done
  }
#undef STAGE

  // epilogue: C/D layout col=lane&15, row=(lane>>4)*4+j; 3-limb X2 split
  const int rb = m0 + wr * 128 + (lane >> 4) * 4;
  const int cb = n0 + wn * 32 + (lane & 15);
#pragma unroll
  for (int mf = 0; mf < 8; ++mf)
#pragma unroll
    for (int nf = 0; nf < 2; ++nf)
#pragma unroll
      for (int j = 0; j < 4; ++j) {
        const int gr = rb + mf * 16 + j;
        const int gc = cb + nf * 16;
        const float v = acc[mf][nf][j];
        const int node = gr & 1023;
        const int coff = (gr >> 10) * 128;  // 0: m_in, 128: m_out
        const int bb = gc >> 7, d = gc & 127;
        bf16* px = X2 + ((size_t)node * 32 + bb) * LDX + coff + d;
        const bf16 l0 = (bf16)v;
        float r = v - (float)l0;
        const bf16 l1 = (bf16)r;
        r -= (float)l1;
        px[0] = l0;
        px[384] = l1;
        px[768] = (bf16)r;
      }
}

// ================= (unchanged below: dense/u5/pack/ew/init from round 4)
static __device__ __forceinline__ void gemm_seg(const bf16* __restrict__ Ao, int lda,
                                                const bf16* __restrict__ Wo, int ldw,
                                                int Kseg, bf16* lA, bf16* lW,
                                                f32x4 (&acc)[4][4]) {
  const int t = threadIdx.x;
  const int wave = t >> 6, lane = t & 63;
  const int wr = wave >> 1, wc = wave & 1;
  const int srow = t >> 2, scol = (t & 3) * 8;
  const int frow = lane & 15, kfr = (lane >> 4) * 8;
  for (int kk = 0; kk < Kseg; kk += 32) {
    const bf16* ga = Ao + (size_t)srow * lda + kk + scol;
    bf16* la = lA + wave * 512;
    gload16(ga, la);
    gload16(ga + (size_t)64 * lda, la + 2048);
    const bf16* gw = Wo + (size_t)srow * ldw + kk + scol;
    bf16* lw = lW + wave * 512;
    gload16(gw, lw);
    gload16(gw + (size_t)64 * ldw, lw + 2048);
    __syncthreads();
    bf16x8 af[4], wf[4];
#pragma unroll
    for (int m = 0; m < 4; ++m)
      af[m] = *(const bf16x8*)(lA + (wr * 64 + m * 16 + frow) * 32 + kfr);
#pragma unroll
    for (int n = 0; n < 4; ++n)
      wf[n] = *(const bf16x8*)(lW + (wc * 64 + n * 16 + frow) * 32 + kfr);
#pragma unroll
    for (int m = 0; m < 4; ++m)
#pragma unroll
      for (int n = 0; n < 4; ++n)
        acc[m][n] = __builtin_amdgcn_mfma_f32_16x16x32_bf16(af[m], wf[n], acc[m][n], 0, 0, 0);
    __syncthreads();
  }
}

#define ACC_ZERO(acc)                          \
  _Pragma("unroll") for (int i = 0; i < 4; ++i) \
  _Pragma("unroll") for (int j = 0; j < 4; ++j) acc[i][j] = {0.f, 0.f, 0.f, 0.f};

#define EPILOG_IDX                                          \
  const int t = threadIdx.x;                                \
  const int wave = t >> 6, lane = t & 63;                   \
  const int rb = (wave >> 1) * 64 + (lane >> 4) * 4;        \
  const int cb = (wave & 1) * 64 + (lane & 15);

__global__ __launch_bounds__(256) void dense_gemm(const bf16* __restrict__ X2,
                                                  const bf16* __restrict__ Wsm,
                                                  const bf16* __restrict__ u3wb,
                                                  const float* __restrict__ u3b,
                                                  float* __restrict__ pre,
                                                  float* __restrict__ u3f) {
  __shared__ bf16 lA[4096];
  __shared__ bf16 lW[4096];
  const int m0 = blockIdx.y * 128;
  const int bx = blockIdx.x;
  f32x4 acc[4][4];
  ACC_ZERO(acc);
  if (bx < 3) {
    const bf16* Ab = X2 + (size_t)m0 * LDX;
    const bf16* Wb = Wsm + (size_t)(bx * 128) * 768;
#pragma unroll
    for (int p = 0; p < 6; ++p)
      gemm_seg(Ab + SA6[p] * 384, LDX, Wb + SB6[p] * 256, 768, 256, lA, lW, acc);
    EPILOG_IDX;
#pragma unroll
    for (int m = 0; m < 4; ++m)
#pragma unroll
      for (int n = 0; n < 4; ++n)
#pragma unroll
        for (int j = 0; j < 4; ++j)
          pre[(size_t)(m0 + rb + m * 16 + j) * 384 + bx * 128 + cb + n * 16] = acc[m][n][j];
  } else {
    const bf16* Ab = X2 + (size_t)m0 * LDX + 256;
#pragma unroll
    for (int p = 0; p < 6; ++p)
      gemm_seg(Ab + SA6[p] * 384, LDX, u3wb + SB6[p] * 128, 384, 128, lA, lW, acc);
    EPILOG_IDX;
#pragma unroll
    for (int m = 0; m < 4; ++m)
#pragma unroll
      for (int n = 0; n < 4; ++n)
#pragma unroll
        for (int j = 0; j < 4; ++j) {
          const int gc = cb + n * 16;
          u3f[(size_t)(m0 + rb + m * 16 + j) * 128 + gc] = acc[m][n][j] + u3b[gc];
        }
  }
}

__global__ __launch_bounds__(256) void u5_gemm(const bf16* __restrict__ rh3,
                                               const bf16* __restrict__ u5wb,
                                               const float* __restrict__ pre,
                                               const float* __restrict__ u3f,
                                               const float* __restrict__ h,
                                               const float* __restrict__ w3b,
                                               const float* __restrict__ w5b,
                                               const float* __restrict__ u5b,
                                               float* __restrict__ out) {
  __shared__ bf16 lA[4096];
  __shared__ bf16 lW[4096];
  const int m0 = blockIdx.y * 128;
  f32x4 acc[4][4];
  ACC_ZERO(acc);
  const bf16* Ab = rh3 + (size_t)m0 * 384;
#pragma unroll
  for (int p = 0; p < 6; ++p)
    gemm_seg(Ab + SA6[p] * 128, 384, u5wb + SB6[p] * 128, 384, 128, lA, lW, acc);
  EPILOG_IDX;
#pragma unroll
  for (int m = 0; m < 4; ++m)
#pragma unroll
    for (int n = 0; n < 2 * 2; ++n) {
    }
#pragma unroll
  for (int m = 0; m < 4; ++m)
#pragma unroll
    for (int n = 0; n < 4; ++n)
#pragma unroll
      for (int j = 0; j < 4; ++j) {
        const int gr = m0 + rb + m * 16 + j;
        const int gc = cb + n * 16;
        const float u5f = acc[m][n][j] + u5b[gc];
        const float z = sigmoidf_((pre[(size_t)gr * 384 + gc] + w3b[gc]) +
                                  u3f[(size_t)gr * 128 + gc]);
        const float hv = tanhf((pre[(size_t)gr * 384 + 256 + gc] + w5b[gc]) + u5f);
        const int bb = gr & 31, node = gr >> 5;
        const size_t hi = ((size_t)bb * 1024 + node) * 128 + gc;
        const float hh = h[hi];
        out[hi] = (1.f - z) * hh + z * hv;
      }
}

__global__ __launch_bounds__(256) void pack_h(const float* __restrict__ h,
                                              bf16* __restrict__ hN2,
                                              bf16* __restrict__ X2) {
  __shared__ unsigned int lds01[128][33];
  __shared__ unsigned short lds2[128][33];
  const int t = threadIdx.x;
  const int b = blockIdx.y;
  const int n0 = blockIdx.x * 32;
#pragma unroll
  for (int i = 0; i < 16; ++i) {
    const int idx = i * 256 + t;
    const int nl = idx >> 7, d = idx & 127;
    const float v = h[((size_t)b * 1024 + n0 + nl) * 128 + d];
    const bf16 l0 = (bf16)v;
    float r = v - (float)l0;
    const bf16 l1 = (bf16)r;
    r -= (float)l1;
    const bf16 l2 = (bf16)r;
    const size_t xr = ((size_t)(n0 + nl) * 32 + b) * LDX + 256 + d;
    X2[xr] = l0;
    X2[xr + 384] = l1;
    X2[xr + 768] = l2;
    lds01[d][nl] = (unsigned)bc16(l0) | ((unsigned)bc16(l1) << 16);
    lds2[d][nl] = bc16(l2);
  }
  __syncthreads();
#pragma unroll
  for (int i = 0; i < 16; ++i) {
    const int idx = i * 256 + t;
    const int d = idx >> 5, nl = idx & 31;
    const unsigned pk = lds01[d][nl];
    const unsigned short s2 = lds2[d][nl];
    bf16* row = hN2 + (size_t)(b * 128 + d) * LDH + n0 + nl;
    row[0] = bcbf((unsigned short)(pk & 0xffffu));
    row[1024] = bcbf((unsigned short)(pk >> 16));
    row[2048] = bcbf(s2);
  }
}

__global__ __launch_bounds__(256) void ew1(const float* __restrict__ pre,
                                           const float* __restrict__ u3f,
                                           const float* __restrict__ h,
                                           const float* __restrict__ w4b,
                                           bf16* __restrict__ rh3) {
  const int e4 = blockIdx.x * 256 + threadIdx.x;
  const int r = e4 >> 5;
  const int dq = (e4 & 31) * 4;
  const int b = r & 31, n = r >> 5;
  const f32x4 p = *(const f32x4*)(pre + (size_t)r * 384 + 128 + dq);
  const f32x4 uf = *(const f32x4*)(u3f + (size_t)r * 128 + dq);
  const f32x4 hh = *(const f32x4*)(h + ((size_t)b * 1024 + n) * 128 + dq);
  const f32x4 b4 = *(const f32x4*)(w4b + dq);
  bf16x4 o0, o1, o2;
#pragma unroll
  for (int j = 0; j < 4; ++j) {
    const float rr = sigmoidf_((p[j] + b4[j]) + uf[j]);
    const float v = rr * hh[j];
    o0[j] = (bf16)v;
    float res = v - (float)o0[j];
    o1[j] = (bf16)res;
    res -= (float)o1[j];
    o2[j] = (bf16)res;
  }
  *(bf16x4*)(rh3 + (size_t)r * 384 + dq) = o0;
  *(bf16x4*)(rh3 + (size_t)r * 384 + 128 + dq) = o1;
  *(bf16x4*)(rh3 + (size_t)r * 384 + 256 + dq) = o2;
}

__global__ __launch_bounds__(256) void split_adj(const float* __restrict__ src,
                                                 bf16* __restrict__ dst) {
  const int i = blockIdx.x * 256 + threadIdx.x;  // 1M
  const int r = i >> 10, c = i & 1023;
  const float v = src[i];
  const bf16 l0 = (bf16)v;
  float rr = v - (float)l0;
  const bf16 l1 = (bf16)rr;
  rr -= (float)l1;
  dst[(size_t)r * LDH + c] = l0;
  dst[(size_t)r * LDH + 1024 + c] = l1;
  dst[(size_t)r * LDH + 2048 + c] = (bf16)rr;
}

__global__ void build_wsm(const float* __restrict__ w3, const float* __restrict__ w4,
                          const float* __restrict__ w5, bf16* __restrict__ Wsm) {
  const int k = blockIdx.x * 128 + threadIdx.x;  // 0..255
  const int j = blockIdx.y;                      // 0..383
  float v;
  if (j < 128) v = w3[j * 256 + k];
  else if (j < 256) v = w4[(j - 128) * 256 + k];
  else v = w5[(j - 256) * 256 + k];
  const bf16 l0 = (bf16)v;
  float rr = v - (float)l0;
  const bf16 l1 = (bf16)rr;
  rr -= (float)l1;
  bf16* row = Wsm + (size_t)j * 768 + k;
  row[0] = l0;
  row[256] = l1;
  row[512] = (bf16)rr;
}

__global__ void build_uw(const float* __restrict__ u, bf16* __restrict__ dst) {
  const int i = blockIdx.x * 256 + threadIdx.x;  // 16384
  const int j = i >> 7, k = i & 127;
  const float v = u[i];
  const bf16 l0 = (bf16)v;
  float rr = v - (float)l0;
  const bf16 l1 = (bf16)rr;
  rr -= (float)l1;
  bf16* row = dst + (size_t)j * 384 + k;
  row[0] = l0;
  row[128] = l1;
  row[256] = (bf16)rr;
}

__global__ void sentinel(float* out, int n) {
  const int i = blockIdx.x * 256 + threadIdx.x;
  if (i < n) out[i] = 123456789.f;
}

extern "C" void kernel_launch(void* const* d_in, const int* in_sizes, int n_in,
                              void* d_out, int out_size, void* d_ws, size_t ws_size,
                              hipStream_t stream) {
  const float* input = (const float*)d_in[0];
  const float* Ain = (const float*)d_in[1];
  const float* Aout = (const float*)d_in[2];
  const float* w3w = (const float*)d_in[3];
  const float* w3b = (const float*)d_in[4];
  const float* u3w = (const float*)d_in[5];
  const float* u3b = (const float*)d_in[6];
  const float* w4w = (const float*)d_in[7];
  const float* w4b = (const float*)d_in[8];
  const float* w5w = (const float*)d_in[9];
  const float* w5b = (const float*)d_in[10];
  const float* u5wf = (const float*)d_in[11];
  const float* u5b = (const float*)d_in[12];
  // d_in[13] = time_step; fixed at 5 by the problem spec.

  char* ws = (char*)d_ws;
  size_t off = 0;
  auto alloc = [&](size_t bytes) -> void* {
    void* p = ws + off;
    off += (bytes + 255) & ~(size_t)255;
    return p;
  };
  bf16* A2 = (bf16*)alloc(2048ull * LDH * 2);   // 12.58 MB
  bf16* hN2 = (bf16*)alloc(4096ull * LDH * 2);  // 25.17 MB (rh3 overlay)
  bf16* X2 = (bf16*)alloc(32768ull * LDX * 2);  // 75.50 MB
  bf16* Wsm = (bf16*)alloc(384ull * 768 * 2);
  bf16* u3wb = (bf16*)alloc(128ull * 384 * 2);
  bf16* u5wb = (bf16*)alloc(128ull * 384 * 2);
  float* pre = (float*)alloc(32768ull * 384 * 4);  // 50.33 MB
  float* u3f = (float*)alloc(32768ull * 128 * 4);  // 16.78 MB
  bf16* rh3 = hN2;  // overlay: ew1 writes after adj8 read hN2; pack_h rewrites
  if (off > ws_size) {
    sentinel<<<dim3((out_size + 255) / 256), dim3(256), 0, stream>>>((float*)d_out, out_size);
    return;
  }

  split_adj<<<dim3(4096), dim3(256), 0, stream>>>(Ain, A2);
  split_adj<<<dim3(4096), dim3(256), 0, stream>>>(Aout, A2 + 1024ull * LDH);
  build_wsm<<<dim3(2, 384), dim3(128), 0, stream>>>(w3w, w4w, w5w, Wsm);
  build_uw<<<dim3(64), dim3(256), 0, stream>>>(u3w, u3wb);
  build_uw<<<dim3(64), dim3(256), 0, stream>>>(u5wf, u5wb);

  float* out = (float*)d_out;
  const float* h = input;
  for (int step = 0; step < 5; ++step) {
    pack_h<<<dim3(32, 32), dim3(256), 0, stream>>>(h, hN2, X2);
    // adjacency: M=2048(in|out), N=4096, virtual-K=6144, direct X2 split
    adj8<<<dim3(32, 8), dim3(512), 0, stream>>>(A2, hN2, X2);
    dense_gemm<<<dim3(4, 256), dim3(256), 0, stream>>>(X2, Wsm, u3wb, u3b, pre, u3f);
    ew1<<<dim3(4096), dim3(256), 0, stream>>>(pre, u3f, h, w4b, rh3);
    u5_gemm<<<dim3(1, 256), dim3(256), 0, stream>>>(rh3, u5wb, pre, u3f, h, w3b, w5b,
                                                    u5b, out);
    h = out;
  }
}